// Round 3
// baseline (2881.133 us; speedup 1.0000x reference)
//
#include <hip/hip_runtime.h>

typedef unsigned int u32;

// SpMM: out[src[e], :] += att[e] * X[dst[e], :]
// edges int32 (2,E): src = edges[0..E), dst = edges[E..2E)
// Two-level plan:
//   1) coarse-bucket counting sort by (src >> 7)  -> 782 buckets of 128 rows
//   2) per-bucket block: LDS fp32 accumulator [128 rows x 128 feats] = 64 KB,
//      stream edges, gather X[dst], LDS atomicAdd, one coalesced tile store.

constexpr int D_FEAT   = 128;
constexpr int BROWS    = 128;               // src rows per bucket
constexpr int N_NODES  = 100000;
constexpr int KBUCKETS = (N_NODES + BROWS - 1) / BROWS;   // 782
constexpr int CHUNK    = 8192;              // edges per scatter chunk

// ---------- 1a: bucket histogram ----------
__global__ __launch_bounds__(256) void bucket_hist(const int* __restrict__ src,
                                                   u32* __restrict__ cnt, int E) {
    __shared__ u32 h[KBUCKETS];
    for (int i = threadIdx.x; i < KBUCKETS; i += 256) h[i] = 0;
    __syncthreads();
    const int stride = gridDim.x * blockDim.x;
    for (int i = blockIdx.x * blockDim.x + threadIdx.x; i < E; i += stride)
        atomicAdd(&h[src[i] >> 7], 1u);
    __syncthreads();
    for (int i = threadIdx.x; i < KBUCKETS; i += 256)
        if (h[i]) atomicAdd(&cnt[i], h[i]);
}

// ---------- 1b: tiny scan over 782 buckets ----------
__global__ __launch_bounds__(256) void bucket_scan(const u32* __restrict__ cnt,
                                                   u32* __restrict__ bptr,
                                                   u32* __restrict__ gcur) {
    __shared__ u32 s[256];
    const int t = threadIdx.x;
    u32 c[4]; u32 tot = 0;
    for (int k = 0; k < 4; ++k) {
        int idx = t * 4 + k;
        c[k] = (idx < KBUCKETS) ? cnt[idx] : 0u;
        tot += c[k];
    }
    s[t] = tot;
    __syncthreads();
    for (int ofs = 1; ofs < 256; ofs <<= 1) {
        u32 v = (t >= ofs) ? s[t - ofs] : 0u;
        __syncthreads();
        s[t] += v;
        __syncthreads();
    }
    u32 run = s[t] - tot;   // exclusive prefix
    for (int k = 0; k < 4; ++k) {
        int idx = t * 4 + k;
        if (idx < KBUCKETS) { bptr[idx] = run; gcur[idx] = run; run += c[k]; }
    }
    if (t == 255) bptr[KBUCKETS] = s[255];
}

// ---------- 1c: counting-sort scatter (chunked, contiguous runs) ----------
__global__ __launch_bounds__(256) void bucket_scatter(const int* __restrict__ src,
                                                      const int* __restrict__ dst,
                                                      const float* __restrict__ att,
                                                      u32* __restrict__ gcur,
                                                      int2* __restrict__ epack, int E) {
    __shared__ u32 lcnt[KBUCKETS];
    __shared__ u32 lbase[KBUCKETS];
    const int nchunks = (E + CHUNK - 1) / CHUNK;
    for (int c = blockIdx.x; c < nchunks; c += gridDim.x) {
        const int e0 = c * CHUNK;
        const int e1 = min(e0 + CHUNK, E);
        for (int i = threadIdx.x; i < KBUCKETS; i += 256) lcnt[i] = 0;
        __syncthreads();
        for (int e = e0 + threadIdx.x; e < e1; e += 256)
            atomicAdd(&lcnt[src[e] >> 7], 1u);
        __syncthreads();
        for (int i = threadIdx.x; i < KBUCKETS; i += 256) {
            u32 n = lcnt[i];
            lbase[i] = n ? atomicAdd(&gcur[i], n) : 0u;
        }
        __syncthreads();
        for (int i = threadIdx.x; i < KBUCKETS; i += 256) lcnt[i] = 0;  // reuse as offset
        __syncthreads();
        for (int e = e0 + threadIdx.x; e < e1; e += 256) {
            const int s = src[e];
            const int b = s >> 7;
            const u32 pos = lbase[b] + atomicAdd(&lcnt[b], 1u);
            // meta: src_local (7b) << 17 | dst (17b)
            epack[pos] = make_int2(((s & 127) << 17) | dst[e], __float_as_int(att[e]));
        }
        __syncthreads();   // protect lcnt reuse in next chunk
    }
}

// ---------- 2: per-bucket LDS accumulate ----------
__global__ __launch_bounds__(512) void accumulate(const u32* __restrict__ bptr,
                                                  const int2* __restrict__ epack,
                                                  const float* __restrict__ X,
                                                  float* __restrict__ out, int N) {
    __shared__ float acc[BROWS * D_FEAT];   // 64 KB
    const int b    = blockIdx.x;
    const int tid  = threadIdx.x;
    const int wave = tid >> 6;
    const int lane = tid & 63;

    for (int i = tid; i < BROWS * D_FEAT; i += 512) acc[i] = 0.f;
    __syncthreads();

    const u32 s = bptr[b];
    const u32 e = bptr[b + 1];

    u32 k = s + wave;
    for (; k + 8 < e; k += 16) {
        const int2 p0 = epack[k];
        const int2 p1 = epack[k + 8];
        const int d0 = p0.x & 0x1FFFF, sl0 = p0.x >> 17;
        const int d1 = p1.x & 0x1FFFF, sl1 = p1.x >> 17;
        const float a0 = __int_as_float(p0.y);
        const float a1 = __int_as_float(p1.y);
        const float* X0 = X + (size_t)d0 * D_FEAT;
        const float* X1 = X + (size_t)d1 * D_FEAT;
        const float v00 = X0[lane], v01 = X0[lane + 64];
        const float v10 = X1[lane], v11 = X1[lane + 64];
        atomicAdd(&acc[sl0 * D_FEAT + lane],      a0 * v00);
        atomicAdd(&acc[sl0 * D_FEAT + lane + 64], a0 * v01);
        atomicAdd(&acc[sl1 * D_FEAT + lane],      a1 * v10);
        atomicAdd(&acc[sl1 * D_FEAT + lane + 64], a1 * v11);
    }
    for (; k < e; k += 8) {
        const int2 p = epack[k];
        const int d = p.x & 0x1FFFF, sl = p.x >> 17;
        const float a = __int_as_float(p.y);
        const float* Xr = X + (size_t)d * D_FEAT;
        atomicAdd(&acc[sl * D_FEAT + lane],      a * Xr[lane]);
        atomicAdd(&acc[sl * D_FEAT + lane + 64], a * Xr[lane + 64]);
    }
    __syncthreads();

    const int row0 = b * BROWS;
    const int rows = min(BROWS, N - row0);
    float4* __restrict__ o4 = (float4*)(out + (size_t)row0 * D_FEAT);
    const float4* a4 = (const float4*)acc;
    for (int i = tid; i < rows * (D_FEAT / 4); i += 512) o4[i] = a4[i];
}

// ---------- Fallback: edge-parallel fp atomics ----------
__global__ __launch_bounds__(256) void spmm_edge_atomic(
    const int* __restrict__ src, const int* __restrict__ dst,
    const float* __restrict__ att, const float* __restrict__ X,
    float* __restrict__ out, int E)
{
    const int group = (int)((blockIdx.x * blockDim.x + threadIdx.x) >> 5);
    const int lane  = threadIdx.x & 31;
    const int nGroups = (int)((gridDim.x * blockDim.x) >> 5);
    for (int e = group; e < E; e += nGroups) {
        const int s = src[e], d = dst[e];
        const float a = att[e];
        const float4 v = ((const float4*)(X + (size_t)d * D_FEAT))[lane];
        float* o = out + (size_t)s * D_FEAT + (size_t)lane * 4;
        unsafeAtomicAdd(o + 0, a * v.x);
        unsafeAtomicAdd(o + 1, a * v.y);
        unsafeAtomicAdd(o + 2, a * v.z);
        unsafeAtomicAdd(o + 3, a * v.w);
    }
}

static inline size_t align16(size_t x) { return (x + 15) & ~(size_t)15; }

extern "C" void kernel_launch(void* const* d_in, const int* in_sizes, int n_in,
                              void* d_out, int out_size, void* d_ws, size_t ws_size,
                              hipStream_t stream) {
    const int*   edges = (const int*)d_in[0];   // (2, E) int32
    const float* att   = (const float*)d_in[1]; // (E,)
    const float* X     = (const float*)d_in[3]; // (N, 128)
    float*       out   = (float*)d_out;

    const int E = in_sizes[1];
    const int N = N_NODES;
    const int* src = edges;
    const int* dst = edges + E;

    // Workspace layout
    size_t o_cnt   = 0;
    size_t o_bptr  = o_cnt  + (size_t)KBUCKETS * 4;
    size_t o_gcur  = o_bptr + ((size_t)KBUCKETS + 1) * 4;
    size_t o_epack = align16(o_gcur + (size_t)KBUCKETS * 4);
    size_t need    = o_epack + (size_t)E * 8;

    if (ws_size < need) {
        hipMemsetAsync(d_out, 0, (size_t)out_size * sizeof(float), stream);
        const int grid = (E + 7) / 8;
        spmm_edge_atomic<<<grid, 256, 0, stream>>>(src, dst, att, X, out, E);
        return;
    }

    char* ws = (char*)d_ws;
    u32*  cnt   = (u32*)(ws + o_cnt);
    u32*  bptr  = (u32*)(ws + o_bptr);
    u32*  gcur  = (u32*)(ws + o_gcur);
    int2* epack = (int2*)(ws + o_epack);

    hipMemsetAsync(cnt, 0, (size_t)KBUCKETS * 4, stream);

    bucket_hist<<<256, 256, 0, stream>>>(src, cnt, E);
    bucket_scan<<<1, 256, 0, stream>>>(cnt, bptr, gcur);
    bucket_scatter<<<256, 256, 0, stream>>>(src, dst, att, gcur, epack, E);
    accumulate<<<KBUCKETS, 512, 0, stream>>>(bptr, epack, X, out, N);
}

// Round 4
// 497.979 us; speedup vs baseline: 5.7856x; 5.7856x over previous
//
#include <hip/hip_runtime.h>

typedef unsigned int u32;

// SpMM: out[src[e], :] += att[e] * X[dst[e], :]
// edges int32 (2,E): src = edges[0..E), dst = edges[E..2E)
// Pipeline:
//   1) coarse counting-sort by bucket = src>>7 (782 buckets of 128 rows);
//      chunked scatter -> contiguous runs -> coalesced-ish writes
//   2) per-bucket block: group edges by row in LDS (int hist+scan+scatter),
//      then one WAVE per row: float2/lane register gather (512B/instr),
//      one coalesced store per row. No fp atomics anywhere.

constexpr int D_FEAT   = 128;
constexpr int BROWS    = 128;
constexpr int N_NODES  = 100000;
constexpr int KBUCKETS = (N_NODES + BROWS - 1) / BROWS;   // 782
constexpr int CHUNK    = 8192;
constexpr int CAP      = 6144;   // LDS edge slots per bucket (mean 4092, sigma 64)

// ---------- 1a: bucket histogram ----------
__global__ __launch_bounds__(256) void bucket_hist(const int* __restrict__ src,
                                                   u32* __restrict__ cnt, int E) {
    __shared__ u32 h[KBUCKETS];
    for (int i = threadIdx.x; i < KBUCKETS; i += 256) h[i] = 0;
    __syncthreads();
    const int stride = gridDim.x * blockDim.x;
    for (int i = blockIdx.x * blockDim.x + threadIdx.x; i < E; i += stride)
        atomicAdd(&h[src[i] >> 7], 1u);
    __syncthreads();
    for (int i = threadIdx.x; i < KBUCKETS; i += 256)
        if (h[i]) atomicAdd(&cnt[i], h[i]);
}

// ---------- 1b: tiny scan over 782 buckets ----------
__global__ __launch_bounds__(256) void bucket_scan(const u32* __restrict__ cnt,
                                                   u32* __restrict__ bptr,
                                                   u32* __restrict__ gcur) {
    __shared__ u32 s[256];
    const int t = threadIdx.x;
    u32 c[4]; u32 tot = 0;
    for (int k = 0; k < 4; ++k) {
        int idx = t * 4 + k;
        c[k] = (idx < KBUCKETS) ? cnt[idx] : 0u;
        tot += c[k];
    }
    s[t] = tot;
    __syncthreads();
    for (int ofs = 1; ofs < 256; ofs <<= 1) {
        u32 v = (t >= ofs) ? s[t - ofs] : 0u;
        __syncthreads();
        s[t] += v;
        __syncthreads();
    }
    u32 run = s[t] - tot;
    for (int k = 0; k < 4; ++k) {
        int idx = t * 4 + k;
        if (idx < KBUCKETS) { bptr[idx] = run; gcur[idx] = run; run += c[k]; }
    }
    if (t == 255) bptr[KBUCKETS] = s[255];
}

// ---------- 1c: counting-sort scatter (chunked, contiguous runs) ----------
__global__ __launch_bounds__(256) void bucket_scatter(const int* __restrict__ src,
                                                      const int* __restrict__ dst,
                                                      const float* __restrict__ att,
                                                      u32* __restrict__ gcur,
                                                      int2* __restrict__ epack, int E) {
    __shared__ u32 lcnt[KBUCKETS];
    __shared__ u32 lbase[KBUCKETS];
    const int nchunks = (E + CHUNK - 1) / CHUNK;
    for (int c = blockIdx.x; c < nchunks; c += gridDim.x) {
        const int e0 = c * CHUNK;
        const int e1 = min(e0 + CHUNK, E);
        for (int i = threadIdx.x; i < KBUCKETS; i += 256) lcnt[i] = 0;
        __syncthreads();
        for (int e = e0 + threadIdx.x; e < e1; e += 256)
            atomicAdd(&lcnt[src[e] >> 7], 1u);
        __syncthreads();
        for (int i = threadIdx.x; i < KBUCKETS; i += 256) {
            u32 n = lcnt[i];
            lbase[i] = n ? atomicAdd(&gcur[i], n) : 0u;
        }
        __syncthreads();
        for (int i = threadIdx.x; i < KBUCKETS; i += 256) lcnt[i] = 0;
        __syncthreads();
        for (int e = e0 + threadIdx.x; e < e1; e += 256) {
            const int s = src[e];
            const int b = s >> 7;
            const u32 pos = lbase[b] + atomicAdd(&lcnt[b], 1u);
            // meta: src_local(7b) << 17 | dst(17b)
            epack[pos] = make_int2(((s & 127) << 17) | dst[e], __float_as_int(att[e]));
        }
        __syncthreads();
    }
}

// ---------- 2: per-bucket group-by-row in LDS + register gather ----------
__global__ __launch_bounds__(512) void accumulate_bucket(
    const u32* __restrict__ bptr, const int2* __restrict__ epack,
    const float* __restrict__ X, float* __restrict__ out, int N)
{
    __shared__ int2 ebuf[CAP];                 // 48 KB
    __shared__ u32 cnt[BROWS], off[BROWS], cur[BROWS];
    const int b    = blockIdx.x;
    const int tid  = threadIdx.x;
    const int wave = tid >> 6;
    const int lane = tid & 63;
    const u32 s = bptr[b], e = bptr[b + 1];
    const int nb = (int)(e - s);
    const int row0 = b * BROWS;
    const int rows = min(BROWS, N - row0);

    if (nb > CAP) {
        // Degenerate path (probability ~0): zero rows, then edge atomics.
        float4* o4 = (float4*)(out + (size_t)row0 * D_FEAT);
        for (int i = tid; i < rows * 32; i += 512) o4[i] = make_float4(0.f,0.f,0.f,0.f);
        __syncthreads();
        const int g = tid >> 5, l32 = tid & 31;
        for (u32 k = s + g; k < e; k += 16) {
            int2 p = epack[k];
            int d = p.x & 0x1FFFF, sl = p.x >> 17;
            float a = __int_as_float(p.y);
            float4 v = ((const float4*)(X + (size_t)d * D_FEAT))[l32];
            float* o = out + (size_t)(row0 + sl) * D_FEAT + l32 * 4;
            unsafeAtomicAdd(o + 0, a * v.x);
            unsafeAtomicAdd(o + 1, a * v.y);
            unsafeAtomicAdd(o + 2, a * v.z);
            unsafeAtomicAdd(o + 3, a * v.w);
        }
        return;
    }

    // (a) per-row histogram
    if (tid < BROWS) cnt[tid] = 0;
    __syncthreads();
    for (int i = tid; i < nb; i += 512)
        atomicAdd(&cnt[(u32)epack[s + i].x >> 17], 1u);
    __syncthreads();

    // (b) exclusive scan of 128 counters by wave 0 (2 counters/lane + shfl)
    if (wave == 0) {
        u32 c0 = cnt[2 * lane], c1 = cnt[2 * lane + 1];
        u32 ps = c0 + c1;
        u32 incl = ps;
        #pragma unroll
        for (int o = 1; o < 64; o <<= 1) {
            u32 v = __shfl_up(incl, o, 64);
            if (lane >= o) incl += v;
        }
        u32 excl = incl - ps;
        off[2 * lane]     = excl;      cur[2 * lane]     = excl;
        off[2 * lane + 1] = excl + c0; cur[2 * lane + 1] = excl + c0;
    }
    __syncthreads();

    // (c) scatter edges into LDS grouped by row
    for (int i = tid; i < nb; i += 512) {
        int2 p = epack[s + i];
        u32 pos = atomicAdd(&cur[(u32)p.x >> 17], 1u);
        ebuf[pos] = p;
    }
    __syncthreads();

    // (d) one wave per row: float2/lane register gather, single store
    for (int r = wave; r < rows; r += 8) {
        const u32 base = off[r];
        const u32 n    = cnt[r];
        float2 acc = make_float2(0.f, 0.f);
        u32 j = 0;
        for (; j + 4 <= n; j += 4) {
            const int2 m0 = ebuf[base + j];
            const int2 m1 = ebuf[base + j + 1];
            const int2 m2 = ebuf[base + j + 2];
            const int2 m3 = ebuf[base + j + 3];
            const float2 v0 = ((const float2*)(X + (size_t)(m0.x & 0x1FFFF) * D_FEAT))[lane];
            const float2 v1 = ((const float2*)(X + (size_t)(m1.x & 0x1FFFF) * D_FEAT))[lane];
            const float2 v2 = ((const float2*)(X + (size_t)(m2.x & 0x1FFFF) * D_FEAT))[lane];
            const float2 v3 = ((const float2*)(X + (size_t)(m3.x & 0x1FFFF) * D_FEAT))[lane];
            const float a0 = __int_as_float(m0.y);
            const float a1 = __int_as_float(m1.y);
            const float a2 = __int_as_float(m2.y);
            const float a3 = __int_as_float(m3.y);
            acc.x = fmaf(a0, v0.x, acc.x); acc.y = fmaf(a0, v0.y, acc.y);
            acc.x = fmaf(a1, v1.x, acc.x); acc.y = fmaf(a1, v1.y, acc.y);
            acc.x = fmaf(a2, v2.x, acc.x); acc.y = fmaf(a2, v2.y, acc.y);
            acc.x = fmaf(a3, v3.x, acc.x); acc.y = fmaf(a3, v3.y, acc.y);
        }
        for (; j < n; ++j) {
            const int2 m = ebuf[base + j];
            const float2 v = ((const float2*)(X + (size_t)(m.x & 0x1FFFF) * D_FEAT))[lane];
            const float a = __int_as_float(m.y);
            acc.x = fmaf(a, v.x, acc.x); acc.y = fmaf(a, v.y, acc.y);
        }
        ((float2*)(out + (size_t)(row0 + r) * D_FEAT))[lane] = acc;
    }
}

// ---------- Fallback: edge-parallel fp atomics ----------
__global__ __launch_bounds__(256) void spmm_edge_atomic(
    const int* __restrict__ src, const int* __restrict__ dst,
    const float* __restrict__ att, const float* __restrict__ X,
    float* __restrict__ out, int E)
{
    const int group = (int)((blockIdx.x * blockDim.x + threadIdx.x) >> 5);
    const int lane  = threadIdx.x & 31;
    const int nGroups = (int)((gridDim.x * blockDim.x) >> 5);
    for (int e = group; e < E; e += nGroups) {
        const int s = src[e], d = dst[e];
        const float a = att[e];
        const float4 v = ((const float4*)(X + (size_t)d * D_FEAT))[lane];
        float* o = out + (size_t)s * D_FEAT + (size_t)lane * 4;
        unsafeAtomicAdd(o + 0, a * v.x);
        unsafeAtomicAdd(o + 1, a * v.y);
        unsafeAtomicAdd(o + 2, a * v.z);
        unsafeAtomicAdd(o + 3, a * v.w);
    }
}

static inline size_t align16(size_t x) { return (x + 15) & ~(size_t)15; }

extern "C" void kernel_launch(void* const* d_in, const int* in_sizes, int n_in,
                              void* d_out, int out_size, void* d_ws, size_t ws_size,
                              hipStream_t stream) {
    const int*   edges = (const int*)d_in[0];   // (2, E) int32
    const float* att   = (const float*)d_in[1]; // (E,)
    const float* X     = (const float*)d_in[3]; // (N, 128)
    float*       out   = (float*)d_out;

    const int E = in_sizes[1];
    const int N = N_NODES;
    const int* src = edges;
    const int* dst = edges + E;

    size_t o_cnt   = 0;
    size_t o_bptr  = o_cnt  + (size_t)KBUCKETS * 4;
    size_t o_gcur  = o_bptr + ((size_t)KBUCKETS + 1) * 4;
    size_t o_epack = align16(o_gcur + (size_t)KBUCKETS * 4);
    size_t need    = o_epack + (size_t)E * 8;

    if (ws_size < need) {
        hipMemsetAsync(d_out, 0, (size_t)out_size * sizeof(float), stream);
        const int grid = (E + 7) / 8;
        spmm_edge_atomic<<<grid, 256, 0, stream>>>(src, dst, att, X, out, E);
        return;
    }

    char* ws = (char*)d_ws;
    u32*  cnt   = (u32*)(ws + o_cnt);
    u32*  bptr  = (u32*)(ws + o_bptr);
    u32*  gcur  = (u32*)(ws + o_gcur);
    int2* epack = (int2*)(ws + o_epack);

    hipMemsetAsync(cnt, 0, (size_t)KBUCKETS * 4, stream);

    bucket_hist<<<256, 256, 0, stream>>>(src, cnt, E);
    bucket_scan<<<1, 256, 0, stream>>>(cnt, bptr, gcur);
    bucket_scatter<<<256, 256, 0, stream>>>(src, dst, att, gcur, epack, E);
    accumulate_bucket<<<KBUCKETS, 512, 0, stream>>>(bptr, epack, X, out, N);
}

// Round 5
// 412.296 us; speedup vs baseline: 6.9880x; 1.2078x over previous
//
#include <hip/hip_runtime.h>

typedef unsigned int u32;

// SpMM: out[src[e], :] += att[e] * X[dst[e], :]
// edges int32 (2,E): src = edges[0..E), dst = edges[E..2E)
// Pipeline:
//   1) coarse counting-sort by bucket = src>>7 (782 buckets of 128 rows)
//   2) per-bucket block: group edges by row in LDS (int hist+scan+scatter),
//      then 32-lane groups: float4/lane register gather (1024 B per wave
//      load instruction, 2 rows/wave), one coalesced store per row.
//      No fp atomics anywhere on the main path.

constexpr int D_FEAT   = 128;
constexpr int BROWS    = 128;
constexpr int N_NODES  = 100000;
constexpr int KBUCKETS = (N_NODES + BROWS - 1) / BROWS;   // 782
constexpr int CHUNK    = 12800;   // edges per scatter block (E/250)
constexpr int CAP      = 4608;    // LDS edge slots (mean 4092, sigma 64 -> +8 sigma)

// ---------- 1a: bucket histogram (16 waves/CU) ----------
__global__ __launch_bounds__(1024) void bucket_hist(const int* __restrict__ src,
                                                    u32* __restrict__ cnt, int E) {
    __shared__ u32 h[KBUCKETS];
    for (int i = threadIdx.x; i < KBUCKETS; i += 1024) h[i] = 0;
    __syncthreads();
    const int stride = gridDim.x * blockDim.x;
    for (int i = blockIdx.x * blockDim.x + threadIdx.x; i < E; i += stride)
        atomicAdd(&h[src[i] >> 7], 1u);
    __syncthreads();
    for (int i = threadIdx.x; i < KBUCKETS; i += 1024)
        if (h[i]) atomicAdd(&cnt[i], h[i]);
}

// ---------- 1b: tiny scan over 782 buckets ----------
__global__ __launch_bounds__(256) void bucket_scan(const u32* __restrict__ cnt,
                                                   u32* __restrict__ bptr,
                                                   u32* __restrict__ gcur) {
    __shared__ u32 s[256];
    const int t = threadIdx.x;
    u32 c[4]; u32 tot = 0;
    for (int k = 0; k < 4; ++k) {
        int idx = t * 4 + k;
        c[k] = (idx < KBUCKETS) ? cnt[idx] : 0u;
        tot += c[k];
    }
    s[t] = tot;
    __syncthreads();
    for (int ofs = 1; ofs < 256; ofs <<= 1) {
        u32 v = (t >= ofs) ? s[t - ofs] : 0u;
        __syncthreads();
        s[t] += v;
        __syncthreads();
    }
    u32 run = s[t] - tot;
    for (int k = 0; k < 4; ++k) {
        int idx = t * 4 + k;
        if (idx < KBUCKETS) { bptr[idx] = run; gcur[idx] = run; run += c[k]; }
    }
    if (t == 255) bptr[KBUCKETS] = s[255];
}

// ---------- 1c: counting-sort scatter, one chunk per block ----------
__global__ __launch_bounds__(1024) void bucket_scatter(const int* __restrict__ src,
                                                       const int* __restrict__ dst,
                                                       const float* __restrict__ att,
                                                       u32* __restrict__ gcur,
                                                       int2* __restrict__ epack, int E) {
    __shared__ u32 lcnt[KBUCKETS];
    __shared__ u32 lbase[KBUCKETS];
    const int e0 = blockIdx.x * CHUNK;
    const int e1 = min(e0 + CHUNK, E);
    for (int i = threadIdx.x; i < KBUCKETS; i += 1024) lcnt[i] = 0;
    __syncthreads();
    for (int e = e0 + threadIdx.x; e < e1; e += 1024)
        atomicAdd(&lcnt[src[e] >> 7], 1u);
    __syncthreads();
    for (int i = threadIdx.x; i < KBUCKETS; i += 1024) {
        u32 n = lcnt[i];
        lbase[i] = n ? atomicAdd(&gcur[i], n) : 0u;
    }
    __syncthreads();
    for (int i = threadIdx.x; i < KBUCKETS; i += 1024) lcnt[i] = 0;
    __syncthreads();
    for (int e = e0 + threadIdx.x; e < e1; e += 1024) {
        const int s = src[e];
        const int b = s >> 7;
        const u32 pos = lbase[b] + atomicAdd(&lcnt[b], 1u);
        // meta: src_local(7b) << 17 | dst(17b)
        epack[pos] = make_int2(((s & 127) << 17) | dst[e], __float_as_int(att[e]));
    }
}

// ---------- 2: per-bucket group-by-row + 32-lane float4 gather ----------
__global__ __launch_bounds__(512, 4) void accumulate_bucket(
    const u32* __restrict__ bptr, const int2* __restrict__ epack,
    const float* __restrict__ X, float* __restrict__ out, int N)
{
    __shared__ int2 ebuf[CAP];                 // 36 KB
    __shared__ u32 cnt[BROWS], off[BROWS], cur[BROWS];
    const int b    = blockIdx.x;
    const int tid  = threadIdx.x;
    const int wave = tid >> 6;
    const int lane = tid & 63;
    const int g    = tid >> 5;                 // 16 groups of 32 lanes
    const int l    = tid & 31;
    const u32 s = bptr[b], e = bptr[b + 1];
    const int nb = (int)(e - s);
    const int row0 = b * BROWS;
    const int rows = min(BROWS, N - row0);

    if (nb > CAP) {
        // Degenerate overflow path (P ~ 1e-15): zero rows, then edge atomics.
        float4* o4 = (float4*)(out + (size_t)row0 * D_FEAT);
        for (int i = tid; i < rows * 32; i += 512) o4[i] = make_float4(0.f,0.f,0.f,0.f);
        __syncthreads();
        for (u32 k = s + g; k < e; k += 16) {
            int2 p = epack[k];
            int d = p.x & 0x1FFFF, sl = p.x >> 17;
            float a = __int_as_float(p.y);
            float4 v = ((const float4*)(X + (size_t)d * D_FEAT))[l];
            float* o = out + (size_t)(row0 + sl) * D_FEAT + l * 4;
            unsafeAtomicAdd(o + 0, a * v.x);
            unsafeAtomicAdd(o + 1, a * v.y);
            unsafeAtomicAdd(o + 2, a * v.z);
            unsafeAtomicAdd(o + 3, a * v.w);
        }
        return;
    }

    // (a) per-row histogram
    if (tid < BROWS) cnt[tid] = 0;
    __syncthreads();
    for (int i = tid; i < nb; i += 512)
        atomicAdd(&cnt[(u32)epack[s + i].x >> 17], 1u);
    __syncthreads();

    // (b) exclusive scan of 128 counters by wave 0
    if (wave == 0) {
        u32 c0 = cnt[2 * lane], c1 = cnt[2 * lane + 1];
        u32 ps = c0 + c1;
        u32 incl = ps;
        #pragma unroll
        for (int o = 1; o < 64; o <<= 1) {
            u32 v = __shfl_up(incl, o, 64);
            if (lane >= o) incl += v;
        }
        u32 excl = incl - ps;
        off[2 * lane]     = excl;      cur[2 * lane]     = excl;
        off[2 * lane + 1] = excl + c0; cur[2 * lane + 1] = excl + c0;
    }
    __syncthreads();

    // (c) scatter edges into LDS grouped by row
    for (int i = tid; i < nb; i += 512) {
        int2 p = epack[s + i];
        u32 pos = atomicAdd(&cur[(u32)p.x >> 17], 1u);
        ebuf[pos] = p;
    }
    __syncthreads();

    // (d) one 32-lane group per row: float4/lane, unroll-4, single store.
    //     A wave's two halves serve two rows -> 1024 B per load instruction.
    const float4* __restrict__ X4 = (const float4*)X;
    for (int r = g; r < rows; r += 16) {
        const u32 base = off[r];
        const u32 n    = cnt[r];
        float4 acc = make_float4(0.f, 0.f, 0.f, 0.f);
        u32 j = 0;
        for (; j + 4 <= n; j += 4) {
            const int2 m0 = ebuf[base + j];
            const int2 m1 = ebuf[base + j + 1];
            const int2 m2 = ebuf[base + j + 2];
            const int2 m3 = ebuf[base + j + 3];
            const float4 v0 = X4[(size_t)(m0.x & 0x1FFFF) * 32 + l];
            const float4 v1 = X4[(size_t)(m1.x & 0x1FFFF) * 32 + l];
            const float4 v2 = X4[(size_t)(m2.x & 0x1FFFF) * 32 + l];
            const float4 v3 = X4[(size_t)(m3.x & 0x1FFFF) * 32 + l];
            const float a0 = __int_as_float(m0.y);
            const float a1 = __int_as_float(m1.y);
            const float a2 = __int_as_float(m2.y);
            const float a3 = __int_as_float(m3.y);
            acc.x = fmaf(a0, v0.x, acc.x); acc.y = fmaf(a0, v0.y, acc.y);
            acc.z = fmaf(a0, v0.z, acc.z); acc.w = fmaf(a0, v0.w, acc.w);
            acc.x = fmaf(a1, v1.x, acc.x); acc.y = fmaf(a1, v1.y, acc.y);
            acc.z = fmaf(a1, v1.z, acc.z); acc.w = fmaf(a1, v1.w, acc.w);
            acc.x = fmaf(a2, v2.x, acc.x); acc.y = fmaf(a2, v2.y, acc.y);
            acc.z = fmaf(a2, v2.z, acc.z); acc.w = fmaf(a2, v2.w, acc.w);
            acc.x = fmaf(a3, v3.x, acc.x); acc.y = fmaf(a3, v3.y, acc.y);
            acc.z = fmaf(a3, v3.z, acc.z); acc.w = fmaf(a3, v3.w, acc.w);
        }
        for (; j < n; ++j) {
            const int2 m = ebuf[base + j];
            const float4 v = X4[(size_t)(m.x & 0x1FFFF) * 32 + l];
            const float a = __int_as_float(m.y);
            acc.x = fmaf(a, v.x, acc.x); acc.y = fmaf(a, v.y, acc.y);
            acc.z = fmaf(a, v.z, acc.z); acc.w = fmaf(a, v.w, acc.w);
        }
        ((float4*)out)[(size_t)(row0 + r) * 32 + l] = acc;
    }
}

// ---------- Fallback: edge-parallel fp atomics ----------
__global__ __launch_bounds__(256) void spmm_edge_atomic(
    const int* __restrict__ src, const int* __restrict__ dst,
    const float* __restrict__ att, const float* __restrict__ X,
    float* __restrict__ out, int E)
{
    const int group = (int)((blockIdx.x * blockDim.x + threadIdx.x) >> 5);
    const int lane  = threadIdx.x & 31;
    const int nGroups = (int)((gridDim.x * blockDim.x) >> 5);
    for (int e = group; e < E; e += nGroups) {
        const int s = src[e], d = dst[e];
        const float a = att[e];
        const float4 v = ((const float4*)(X + (size_t)d * D_FEAT))[lane];
        float* o = out + (size_t)s * D_FEAT + (size_t)lane * 4;
        unsafeAtomicAdd(o + 0, a * v.x);
        unsafeAtomicAdd(o + 1, a * v.y);
        unsafeAtomicAdd(o + 2, a * v.z);
        unsafeAtomicAdd(o + 3, a * v.w);
    }
}

static inline size_t align16(size_t x) { return (x + 15) & ~(size_t)15; }

extern "C" void kernel_launch(void* const* d_in, const int* in_sizes, int n_in,
                              void* d_out, int out_size, void* d_ws, size_t ws_size,
                              hipStream_t stream) {
    const int*   edges = (const int*)d_in[0];   // (2, E) int32
    const float* att   = (const float*)d_in[1]; // (E,)
    const float* X     = (const float*)d_in[3]; // (N, 128)
    float*       out   = (float*)d_out;

    const int E = in_sizes[1];
    const int N = N_NODES;
    const int* src = edges;
    const int* dst = edges + E;

    size_t o_cnt   = 0;
    size_t o_bptr  = o_cnt  + (size_t)KBUCKETS * 4;
    size_t o_gcur  = o_bptr + ((size_t)KBUCKETS + 1) * 4;
    size_t o_epack = align16(o_gcur + (size_t)KBUCKETS * 4);
    size_t need    = o_epack + (size_t)E * 8;

    if (ws_size < need) {
        hipMemsetAsync(d_out, 0, (size_t)out_size * sizeof(float), stream);
        const int grid = (E + 7) / 8;
        spmm_edge_atomic<<<grid, 256, 0, stream>>>(src, dst, att, X, out, E);
        return;
    }

    char* ws = (char*)d_ws;
    u32*  cnt   = (u32*)(ws + o_cnt);
    u32*  bptr  = (u32*)(ws + o_bptr);
    u32*  gcur  = (u32*)(ws + o_gcur);
    int2* epack = (int2*)(ws + o_epack);

    hipMemsetAsync(cnt, 0, (size_t)KBUCKETS * 4, stream);

    bucket_hist<<<256, 1024, 0, stream>>>(src, cnt, E);
    bucket_scan<<<1, 256, 0, stream>>>(cnt, bptr, gcur);
    const int nchunks = (E + CHUNK - 1) / CHUNK;
    bucket_scatter<<<nchunks, 1024, 0, stream>>>(src, dst, att, gcur, epack, E);
    accumulate_bucket<<<KBUCKETS, 512, 0, stream>>>(bptr, epack, X, out, N);
}

// Round 6
// 350.411 us; speedup vs baseline: 8.2222x; 1.1766x over previous
//
#include <hip/hip_runtime.h>

typedef unsigned int u32;

// SpMM: out[src[e], :] += att[e] * X[dst[e], :]
// edges int32 (2,E): src = edges[0..E), dst = edges[E..2E)
// Pipeline:
//   0) X (fp32) -> Xb (bf16, RNE) once per call: halves gather bytes
//   1) coarse counting-sort by bucket = src>>7 (782 buckets of 128 rows)
//   2) per-bucket block: group edges by row in LDS, then 32-lane groups
//      gather bf16 rows (256 B per group load), fp32 register accumulate,
//      one coalesced fp32 store per row. No fp atomics on the main path.

constexpr int D_FEAT   = 128;
constexpr int BROWS    = 128;
constexpr int N_NODES  = 100000;
constexpr int KBUCKETS = (N_NODES + BROWS - 1) / BROWS;   // 782
constexpr int CHUNK    = 16384;
constexpr int CAP      = 4608;    // LDS edge slots (mean 4092, sigma 64 -> +8 sigma)

__device__ __forceinline__ u32 rne_bf16(float f) {
    u32 u = __float_as_uint(f);
    return (u + 0x7FFFu + ((u >> 16) & 1u)) >> 16;
}

// ---------- 0: X -> bf16 ----------
__global__ __launch_bounds__(256) void x_to_bf16(const float4* __restrict__ X4,
                                                 uint2* __restrict__ Xb, int n4) {
    int i = blockIdx.x * blockDim.x + threadIdx.x;
    if (i < n4) {
        float4 v = X4[i];
        uint2 o;
        o.x = rne_bf16(v.x) | (rne_bf16(v.y) << 16);
        o.y = rne_bf16(v.z) | (rne_bf16(v.w) << 16);
        Xb[i] = o;
    }
}

// ---------- 1a: bucket histogram (vectorized reads) ----------
__global__ __launch_bounds__(1024) void bucket_hist(const int* __restrict__ src,
                                                    u32* __restrict__ cnt, int E) {
    __shared__ u32 h[KBUCKETS];
    for (int i = threadIdx.x; i < KBUCKETS; i += 1024) h[i] = 0;
    __syncthreads();
    const int stride4 = gridDim.x * blockDim.x * 4;
    const int nfull = E & ~3;
    for (int i = (blockIdx.x * blockDim.x + threadIdx.x) * 4; i < nfull; i += stride4) {
        int4 s4 = *(const int4*)(src + i);
        atomicAdd(&h[s4.x >> 7], 1u);
        atomicAdd(&h[s4.y >> 7], 1u);
        atomicAdd(&h[s4.z >> 7], 1u);
        atomicAdd(&h[s4.w >> 7], 1u);
    }
    for (int i = nfull + blockIdx.x * blockDim.x + threadIdx.x; i < E;
         i += gridDim.x * blockDim.x)
        atomicAdd(&h[src[i] >> 7], 1u);
    __syncthreads();
    for (int i = threadIdx.x; i < KBUCKETS; i += 1024)
        if (h[i]) atomicAdd(&cnt[i], h[i]);
}

// ---------- 1b: tiny scan over 782 buckets ----------
__global__ __launch_bounds__(256) void bucket_scan(const u32* __restrict__ cnt,
                                                   u32* __restrict__ bptr,
                                                   u32* __restrict__ gcur) {
    __shared__ u32 s[256];
    const int t = threadIdx.x;
    u32 c[4]; u32 tot = 0;
    for (int k = 0; k < 4; ++k) {
        int idx = t * 4 + k;
        c[k] = (idx < KBUCKETS) ? cnt[idx] : 0u;
        tot += c[k];
    }
    s[t] = tot;
    __syncthreads();
    for (int ofs = 1; ofs < 256; ofs <<= 1) {
        u32 v = (t >= ofs) ? s[t - ofs] : 0u;
        __syncthreads();
        s[t] += v;
        __syncthreads();
    }
    u32 run = s[t] - tot;
    for (int k = 0; k < 4; ++k) {
        int idx = t * 4 + k;
        if (idx < KBUCKETS) { bptr[idx] = run; gcur[idx] = run; run += c[k]; }
    }
    if (t == 255) bptr[KBUCKETS] = s[255];
}

// ---------- 1c: counting-sort scatter (vectorized reads) ----------
__global__ __launch_bounds__(1024) void bucket_scatter(const int* __restrict__ src,
                                                       const int* __restrict__ dst,
                                                       const float* __restrict__ att,
                                                       u32* __restrict__ gcur,
                                                       int2* __restrict__ epack, int E) {
    __shared__ u32 lcnt[KBUCKETS];
    __shared__ u32 lbase[KBUCKETS];
    const int e0 = blockIdx.x * CHUNK;
    const int e1 = min(e0 + CHUNK, E);
    const int n  = e1 - e0;
    const int nfull = n & ~3;
    const bool v4ok = ((E & 3) == 0);   // dst = edges+E alignment for int4

    for (int i = threadIdx.x; i < KBUCKETS; i += 1024) lcnt[i] = 0;
    __syncthreads();
    if (v4ok) {
        for (int o = threadIdx.x * 4; o < nfull; o += 4096) {
            int4 s4 = *(const int4*)(src + e0 + o);
            atomicAdd(&lcnt[s4.x >> 7], 1u);
            atomicAdd(&lcnt[s4.y >> 7], 1u);
            atomicAdd(&lcnt[s4.z >> 7], 1u);
            atomicAdd(&lcnt[s4.w >> 7], 1u);
        }
        for (int o = nfull + threadIdx.x; o < n; o += 1024)
            atomicAdd(&lcnt[src[e0 + o] >> 7], 1u);
    } else {
        for (int o = threadIdx.x; o < n; o += 1024)
            atomicAdd(&lcnt[src[e0 + o] >> 7], 1u);
    }
    __syncthreads();
    for (int i = threadIdx.x; i < KBUCKETS; i += 1024) {
        u32 c = lcnt[i];
        lbase[i] = c ? atomicAdd(&gcur[i], c) : 0u;
    }
    __syncthreads();
    for (int i = threadIdx.x; i < KBUCKETS; i += 1024) lcnt[i] = 0;
    __syncthreads();
    if (v4ok) {
        for (int o = threadIdx.x * 4; o < nfull; o += 4096) {
            int4   s4 = *(const int4*)(src + e0 + o);
            int4   d4 = *(const int4*)(dst + e0 + o);
            float4 a4 = *(const float4*)(att + e0 + o);
            #pragma unroll
            for (int k = 0; k < 4; ++k) {
                int s  = (&s4.x)[k];
                int d  = (&d4.x)[k];
                float a = (&a4.x)[k];
                int b  = s >> 7;
                u32 pos = lbase[b] + atomicAdd(&lcnt[b], 1u);
                epack[pos] = make_int2(((s & 127) << 17) | d, __float_as_int(a));
            }
        }
        for (int o = nfull + threadIdx.x; o < n; o += 1024) {
            int s = src[e0 + o], b = s >> 7;
            u32 pos = lbase[b] + atomicAdd(&lcnt[b], 1u);
            epack[pos] = make_int2(((s & 127) << 17) | dst[e0 + o],
                                   __float_as_int(att[e0 + o]));
        }
    } else {
        for (int o = threadIdx.x; o < n; o += 1024) {
            int s = src[e0 + o], b = s >> 7;
            u32 pos = lbase[b] + atomicAdd(&lcnt[b], 1u);
            epack[pos] = make_int2(((s & 127) << 17) | dst[e0 + o],
                                   __float_as_int(att[e0 + o]));
        }
    }
}

// ---------- shared LDS regroup for accumulate ----------
#define REGROUP_BODY()                                                         \
    if (tid < BROWS) cnt[tid] = 0;                                             \
    __syncthreads();                                                           \
    for (int i = tid; i < nb; i += 512)                                        \
        atomicAdd(&cnt[(u32)epack[s + i].x >> 17], 1u);                        \
    __syncthreads();                                                           \
    if (wave == 0) {                                                           \
        u32 c0 = cnt[2 * lane], c1 = cnt[2 * lane + 1];                        \
        u32 ps = c0 + c1;                                                      \
        u32 incl = ps;                                                         \
        _Pragma("unroll")                                                      \
        for (int o = 1; o < 64; o <<= 1) {                                     \
            u32 v = __shfl_up(incl, o, 64);                                    \
            if (lane >= o) incl += v;                                          \
        }                                                                      \
        u32 excl = incl - ps;                                                  \
        off[2 * lane]     = excl;      cur[2 * lane]     = excl;               \
        off[2 * lane + 1] = excl + c0; cur[2 * lane + 1] = excl + c0;          \
    }                                                                          \
    __syncthreads();                                                           \
    for (int i = tid; i < nb; i += 512) {                                      \
        int2 p = epack[s + i];                                                 \
        u32 pos = atomicAdd(&cur[(u32)p.x >> 17], 1u);                         \
        ebuf[pos] = p;                                                         \
    }                                                                          \
    __syncthreads();

// ---------- 2 (bf16): per-bucket regroup + 32-lane bf16 gather ----------
__global__ __launch_bounds__(512, 4) void accumulate_bucket_bf16(
    const u32* __restrict__ bptr, const int2* __restrict__ epack,
    const uint2* __restrict__ Xb, const float* __restrict__ X,
    float* __restrict__ out, int N)
{
    __shared__ int2 ebuf[CAP];
    __shared__ u32 cnt[BROWS], off[BROWS], cur[BROWS];
    const int b    = blockIdx.x;
    const int tid  = threadIdx.x;
    const int wave = tid >> 6;
    const int lane = tid & 63;
    const int g    = tid >> 5;
    const int l    = tid & 31;
    const u32 s = bptr[b], e = bptr[b + 1];
    const int nb = (int)(e - s);
    const int row0 = b * BROWS;
    const int rows = min(BROWS, N - row0);

    if (nb > CAP) {
        // Degenerate overflow path: zero rows, then fp32 edge atomics.
        float4* o4 = (float4*)(out + (size_t)row0 * D_FEAT);
        for (int i = tid; i < rows * 32; i += 512) o4[i] = make_float4(0.f,0.f,0.f,0.f);
        __syncthreads();
        for (u32 k = s + g; k < e; k += 16) {
            int2 p = epack[k];
            int d = p.x & 0x1FFFF, sl = p.x >> 17;
            float a = __int_as_float(p.y);
            float4 v = ((const float4*)(X + (size_t)d * D_FEAT))[l];
            float* o = out + (size_t)(row0 + sl) * D_FEAT + l * 4;
            unsafeAtomicAdd(o + 0, a * v.x);
            unsafeAtomicAdd(o + 1, a * v.y);
            unsafeAtomicAdd(o + 2, a * v.z);
            unsafeAtomicAdd(o + 3, a * v.w);
        }
        return;
    }

    REGROUP_BODY()

    // one 32-lane group per row: uint2 = 4 bf16 per lane, unroll-8
    for (int r = g; r < rows; r += 16) {
        const u32 base = off[r];
        const u32 n    = cnt[r];
        float4 acc = make_float4(0.f, 0.f, 0.f, 0.f);
        u32 j = 0;
        for (; j + 8 <= n; j += 8) {
            uint2 q[8]; float a[8];
            #pragma unroll
            for (int k = 0; k < 8; ++k) {
                const int2 m = ebuf[base + j + k];
                q[k] = Xb[(size_t)(m.x & 0x1FFFF) * 32 + l];
                a[k] = __int_as_float(m.y);
            }
            #pragma unroll
            for (int k = 0; k < 8; ++k) {
                acc.x = fmaf(a[k], __uint_as_float(q[k].x << 16),          acc.x);
                acc.y = fmaf(a[k], __uint_as_float(q[k].x & 0xFFFF0000u),  acc.y);
                acc.z = fmaf(a[k], __uint_as_float(q[k].y << 16),          acc.z);
                acc.w = fmaf(a[k], __uint_as_float(q[k].y & 0xFFFF0000u),  acc.w);
            }
        }
        for (; j + 2 <= n; j += 2) {
            const int2 m0 = ebuf[base + j];
            const int2 m1 = ebuf[base + j + 1];
            const uint2 q0 = Xb[(size_t)(m0.x & 0x1FFFF) * 32 + l];
            const uint2 q1 = Xb[(size_t)(m1.x & 0x1FFFF) * 32 + l];
            const float a0 = __int_as_float(m0.y);
            const float a1 = __int_as_float(m1.y);
            acc.x = fmaf(a0, __uint_as_float(q0.x << 16),         acc.x);
            acc.y = fmaf(a0, __uint_as_float(q0.x & 0xFFFF0000u), acc.y);
            acc.z = fmaf(a0, __uint_as_float(q0.y << 16),         acc.z);
            acc.w = fmaf(a0, __uint_as_float(q0.y & 0xFFFF0000u), acc.w);
            acc.x = fmaf(a1, __uint_as_float(q1.x << 16),         acc.x);
            acc.y = fmaf(a1, __uint_as_float(q1.x & 0xFFFF0000u), acc.y);
            acc.z = fmaf(a1, __uint_as_float(q1.y << 16),         acc.z);
            acc.w = fmaf(a1, __uint_as_float(q1.y & 0xFFFF0000u), acc.w);
        }
        if (j < n) {
            const int2 m = ebuf[base + j];
            const uint2 q = Xb[(size_t)(m.x & 0x1FFFF) * 32 + l];
            const float a = __int_as_float(m.y);
            acc.x = fmaf(a, __uint_as_float(q.x << 16),         acc.x);
            acc.y = fmaf(a, __uint_as_float(q.x & 0xFFFF0000u), acc.y);
            acc.z = fmaf(a, __uint_as_float(q.y << 16),         acc.z);
            acc.w = fmaf(a, __uint_as_float(q.y & 0xFFFF0000u), acc.w);
        }
        ((float4*)out)[(size_t)(row0 + r) * 32 + l] = acc;
    }
}

// ---------- 2 (fp32, round-5): fallback when ws can't hold Xb ----------
__global__ __launch_bounds__(512, 4) void accumulate_bucket_f32(
    const u32* __restrict__ bptr, const int2* __restrict__ epack,
    const float* __restrict__ X, float* __restrict__ out, int N)
{
    __shared__ int2 ebuf[CAP];
    __shared__ u32 cnt[BROWS], off[BROWS], cur[BROWS];
    const int b    = blockIdx.x;
    const int tid  = threadIdx.x;
    const int wave = tid >> 6;
    const int lane = tid & 63;
    const int g    = tid >> 5;
    const int l    = tid & 31;
    const u32 s = bptr[b], e = bptr[b + 1];
    const int nb = (int)(e - s);
    const int row0 = b * BROWS;
    const int rows = min(BROWS, N - row0);

    if (nb > CAP) {
        float4* o4 = (float4*)(out + (size_t)row0 * D_FEAT);
        for (int i = tid; i < rows * 32; i += 512) o4[i] = make_float4(0.f,0.f,0.f,0.f);
        __syncthreads();
        for (u32 k = s + g; k < e; k += 16) {
            int2 p = epack[k];
            int d = p.x & 0x1FFFF, sl = p.x >> 17;
            float a = __int_as_float(p.y);
            float4 v = ((const float4*)(X + (size_t)d * D_FEAT))[l];
            float* o = out + (size_t)(row0 + sl) * D_FEAT + l * 4;
            unsafeAtomicAdd(o + 0, a * v.x);
            unsafeAtomicAdd(o + 1, a * v.y);
            unsafeAtomicAdd(o + 2, a * v.z);
            unsafeAtomicAdd(o + 3, a * v.w);
        }
        return;
    }

    REGROUP_BODY()

    const float4* __restrict__ X4 = (const float4*)X;
    for (int r = g; r < rows; r += 16) {
        const u32 base = off[r];
        const u32 n    = cnt[r];
        float4 acc = make_float4(0.f, 0.f, 0.f, 0.f);
        u32 j = 0;
        for (; j + 4 <= n; j += 4) {
            const int2 m0 = ebuf[base + j];
            const int2 m1 = ebuf[base + j + 1];
            const int2 m2 = ebuf[base + j + 2];
            const int2 m3 = ebuf[base + j + 3];
            const float4 v0 = X4[(size_t)(m0.x & 0x1FFFF) * 32 + l];
            const float4 v1 = X4[(size_t)(m1.x & 0x1FFFF) * 32 + l];
            const float4 v2 = X4[(size_t)(m2.x & 0x1FFFF) * 32 + l];
            const float4 v3 = X4[(size_t)(m3.x & 0x1FFFF) * 32 + l];
            const float a0 = __int_as_float(m0.y);
            const float a1 = __int_as_float(m1.y);
            const float a2 = __int_as_float(m2.y);
            const float a3 = __int_as_float(m3.y);
            acc.x = fmaf(a0, v0.x, acc.x); acc.y = fmaf(a0, v0.y, acc.y);
            acc.z = fmaf(a0, v0.z, acc.z); acc.w = fmaf(a0, v0.w, acc.w);
            acc.x = fmaf(a1, v1.x, acc.x); acc.y = fmaf(a1, v1.y, acc.y);
            acc.z = fmaf(a1, v1.z, acc.z); acc.w = fmaf(a1, v1.w, acc.w);
            acc.x = fmaf(a2, v2.x, acc.x); acc.y = fmaf(a2, v2.y, acc.y);
            acc.z = fmaf(a2, v2.z, acc.z); acc.w = fmaf(a2, v2.w, acc.w);
            acc.x = fmaf(a3, v3.x, acc.x); acc.y = fmaf(a3, v3.y, acc.y);
            acc.z = fmaf(a3, v3.z, acc.z); acc.w = fmaf(a3, v3.w, acc.w);
        }
        for (; j < n; ++j) {
            const int2 m = ebuf[base + j];
            const float4 v = X4[(size_t)(m.x & 0x1FFFF) * 32 + l];
            const float a = __int_as_float(m.y);
            acc.x = fmaf(a, v.x, acc.x); acc.y = fmaf(a, v.y, acc.y);
            acc.z = fmaf(a, v.z, acc.z); acc.w = fmaf(a, v.w, acc.w);
        }
        ((float4*)out)[(size_t)(row0 + r) * 32 + l] = acc;
    }
}

// ---------- last-resort fallback: edge-parallel fp atomics ----------
__global__ __launch_bounds__(256) void spmm_edge_atomic(
    const int* __restrict__ src, const int* __restrict__ dst,
    const float* __restrict__ att, const float* __restrict__ X,
    float* __restrict__ out, int E)
{
    const int group = (int)((blockIdx.x * blockDim.x + threadIdx.x) >> 5);
    const int lane  = threadIdx.x & 31;
    const int nGroups = (int)((gridDim.x * blockDim.x) >> 5);
    for (int e = group; e < E; e += nGroups) {
        const int s = src[e], d = dst[e];
        const float a = att[e];
        const float4 v = ((const float4*)(X + (size_t)d * D_FEAT))[lane];
        float* o = out + (size_t)s * D_FEAT + (size_t)lane * 4;
        unsafeAtomicAdd(o + 0, a * v.x);
        unsafeAtomicAdd(o + 1, a * v.y);
        unsafeAtomicAdd(o + 2, a * v.z);
        unsafeAtomicAdd(o + 3, a * v.w);
    }
}

static inline size_t align16(size_t x) { return (x + 15) & ~(size_t)15; }

extern "C" void kernel_launch(void* const* d_in, const int* in_sizes, int n_in,
                              void* d_out, int out_size, void* d_ws, size_t ws_size,
                              hipStream_t stream) {
    const int*   edges = (const int*)d_in[0];   // (2, E) int32
    const float* att   = (const float*)d_in[1]; // (E,)
    const float* X     = (const float*)d_in[3]; // (N, 128)
    float*       out   = (float*)d_out;

    const int E = in_sizes[1];
    const int N = N_NODES;
    const int* src = edges;
    const int* dst = edges + E;

    size_t o_cnt   = 0;
    size_t o_bptr  = o_cnt  + (size_t)KBUCKETS * 4;
    size_t o_gcur  = o_bptr + ((size_t)KBUCKETS + 1) * 4;
    size_t o_epack = align16(o_gcur + (size_t)KBUCKETS * 4);
    size_t o_xb    = o_epack + (size_t)E * 8;
    size_t need_f32  = o_xb;
    size_t need_bf16 = o_xb + (size_t)N * D_FEAT * 2;

    if (ws_size < need_f32) {
        hipMemsetAsync(d_out, 0, (size_t)out_size * sizeof(float), stream);
        const int grid = (E + 7) / 8;
        spmm_edge_atomic<<<grid, 256, 0, stream>>>(src, dst, att, X, out, E);
        return;
    }

    char* ws = (char*)d_ws;
    u32*   cnt   = (u32*)(ws + o_cnt);
    u32*   bptr  = (u32*)(ws + o_bptr);
    u32*   gcur  = (u32*)(ws + o_gcur);
    int2*  epack = (int2*)(ws + o_epack);
    uint2* Xb    = (uint2*)(ws + o_xb);

    hipMemsetAsync(cnt, 0, (size_t)KBUCKETS * 4, stream);

    const bool use_bf16 = (ws_size >= need_bf16);
    if (use_bf16) {
        const int n4 = (N * D_FEAT) / 4;
        x_to_bf16<<<(n4 + 255) / 256, 256, 0, stream>>>((const float4*)X, Xb, n4);
    }

    bucket_hist<<<256, 1024, 0, stream>>>(src, cnt, E);
    bucket_scan<<<1, 256, 0, stream>>>(cnt, bptr, gcur);
    const int nchunks = (E + CHUNK - 1) / CHUNK;
    bucket_scatter<<<nchunks, 1024, 0, stream>>>(src, dst, att, gcur, epack, E);

    if (use_bf16)
        accumulate_bucket_bf16<<<KBUCKETS, 512, 0, stream>>>(bptr, epack, Xb, X, out, N);
    else
        accumulate_bucket_f32<<<KBUCKETS, 512, 0, stream>>>(bptr, epack, X, out, N);
}